// Round 10
// baseline (484.162 us; speedup 1.0000x reference)
//
#include <hip/hip_runtime.h>
#include <hip/hip_cooperative_groups.h>
#include <math.h>

namespace cg = cooperative_groups;

#define BB 2
#define TT 2048
#define EE 1024
#define HH 16
#define DD 64
#define MM (BB*TT)   // 4096
#define KK EE        // 1024

typedef short bf16x8 __attribute__((ext_vector_type(8)));
typedef float f32x4  __attribute__((ext_vector_type(4)));
typedef float f32x16 __attribute__((ext_vector_type(16)));
typedef unsigned int u32x4 __attribute__((ext_vector_type(4)));

// round-to-nearest-even fp32 -> bf16 (as ushort)
__device__ __forceinline__ unsigned short f2bf(float f) {
  unsigned int u = __float_as_uint(f);
  u = (u + 0x7FFFu + ((u >> 16) & 1u)) >> 16;
  return (unsigned short)u;
}

// packed RNE fp32x2 -> bf16x2 (low = lo)
__device__ __forceinline__ unsigned int cvtpk(float lo, float hi) {
  unsigned int r;
  asm("v_cvt_pk_bf16_f32 %0, %1, %2" : "=v"(r) : "v"(lo), "v"(hi));
  return r;
}

// (a,b) -> a = {a_lo, b_lo}, b = {a_hi, b_hi}  (32-lane half swap)
__device__ __forceinline__ void plswap(unsigned int &a, unsigned int &b) {
  asm("v_permlane32_swap_b32 %0, %1" : "+v"(a), "+v"(b));
}

// async global->LDS DMA, 16B per lane, LDS dest = wave-uniform base + lane*16
__device__ __forceinline__ void async16(const void* g, void* l) {
  __builtin_amdgcn_global_load_lds(
      (const __attribute__((address_space(1))) unsigned int*)g,
      (__attribute__((address_space(3))) unsigned int*)l, 16, 0, 0);
}

// ---------------------------------------------------------------------------
// bf16 MFMA GEMM tile body (R9 code, re-indexed for fused kernels).
// 512 threads / 8 waves (4m x 2n wave grid, 32-row wave tiles). Triple-
// buffered single-barrier pipeline, 1-ahead staging; depth-XOR LDS placement
// slot = c ^ (row&3) ^ ((row>>2)&3) (bank-conflict-free, verified R9:
// SQ_LDS_BANK_CONFLICT -> 0). Trailing __syncthreads() protects S reuse
// when a block loops over multiple tiles (grid-stride).
// MODE 0: fused QKV, tile 128x128, N=3072. MODE 2: fp32 out, tile 128x64.
// ---------------------------------------------------------------------------
template<int MODE>
__device__ __forceinline__ void gemm_body(
    unsigned short* S, int m0, int n0,
    const unsigned short* A, const unsigned short* B,
    const float* b0p, const float* b1p, const float* b2p,
    unsigned short* oq, unsigned short* ok, unsigned short* ov,
    float* ofp, float qscale)
{
  constexpr int NT = (MODE == 0) ? 128 : 64;   // n-tile
  constexpr int JN = NT / 32;                  // j-frags per wave (4 / 2)
  constexpr int BROWS = NT * 32;               // B-buffer ushorts per slot
  constexpr int TOT = (MODE == 0) ? 16 : 12;   // staging chunks per K-step

  const int tid  = threadIdx.x;
  const int lane = tid & 63;
  const int wv   = tid >> 6;                   // 0..7
  const int col  = lane & 15;
  const int quad = lane >> 4;
  const int wm = (wv & 3) * 32;
  const int wn = (wv >> 2) * (NT / 2);

  const int srow = lane >> 2;                                // 16 rows/call
  const int sw16 = (((lane & 3) ^ ((lane >> 2) & 3) ^ (lane >> 4)) << 3);
  const int fswA = ((quad ^ (col & 3) ^ (col >> 2)) << 3);

  auto stage = [&](int kt, int slot) {
#pragma unroll
    for (int s = 0; s < 2; ++s) {
      const int t = wv * 2 + s;
      if (t < TOT) {
        const unsigned short* src; int rb, g0, loff;
        if (t < 8) { src = A; rb = t * 16;       g0 = m0; loff = slot * 4096; }
        else       { src = B; rb = (t - 8) * 16; g0 = n0; loff = 12288 + slot * BROWS; }
        async16(src + (size_t)(g0 + rb + srow) * KK + kt + sw16,
                S + loff + rb * 32);
      }
    }
  };

  f32x4 acc[2][JN];
  const f32x4 z = {0.f, 0.f, 0.f, 0.f};
#pragma unroll
  for (int i = 0; i < 2; ++i)
#pragma unroll
    for (int j = 0; j < JN; ++j) acc[i][j] = z;

  stage(0, 0);

#define GBODY(T, SL, S2, DOSTAGE, VMC) do {                                   \
    if (DOSTAGE) stage(((T) + 1) * 32, S2);                                   \
    asm volatile("s_waitcnt vmcnt(" #VMC ")" ::: "memory");                   \
    __builtin_amdgcn_sched_barrier(0);                                        \
    __builtin_amdgcn_s_barrier();                                             \
    __builtin_amdgcn_sched_barrier(0);                                        \
    const unsigned short* Asb = S + (SL) * 4096;                              \
    const unsigned short* Bsb = S + 12288 + (SL) * BROWS;                     \
    bf16x8 bfr[JN];                                                           \
    _Pragma("unroll")                                                         \
    for (int j = 0; j < JN; ++j)                                              \
      bfr[j] = *(const bf16x8*)(Bsb + (wn + j * 16 + col) * 32 + fswA);       \
    _Pragma("unroll")                                                         \
    for (int i = 0; i < 2; ++i) {                                             \
      bf16x8 af = *(const bf16x8*)(Asb + (wm + i * 16 + col) * 32 + fswA);    \
      _Pragma("unroll")                                                       \
      for (int j = 0; j < JN; ++j)                                            \
        acc[i][j] = __builtin_amdgcn_mfma_f32_16x16x32_bf16(af, bfr[j], acc[i][j], 0, 0, 0); \
    }                                                                         \
  } while (0)

  for (int t = 0; t < 30; t += 3) {
    GBODY(t + 0, 0, 1, 1, 2);
    GBODY(t + 1, 1, 2, 1, 2);
    GBODY(t + 2, 2, 0, 1, 2);
  }
  GBODY(30, 0, 1, 1, 2);
  GBODY(31, 1, 0, 0, 0);
#undef GBODY

  // Epilogue. C/D: row = quad*4+r, col = lane&15 per 16x16 tile.
  unsigned short* Cs = S;
  if (MODE == 0) {
    __syncthreads();   // all waves done reading slots before Cs alias writes
    const int region = n0 >> 10;   // block-uniform: 0=Q, 1=K, 2=V
    const float* bias = (region == 0) ? b0p : (region == 1) ? b1p : b2p;
    const float scl = (region == 0) ? qscale : 1.0f;
    const int nlbase = n0 & 1023;
    const int h0 = nlbase >> 6;
    const int b = m0 >> 11, t0 = m0 & (TT - 1);
    if (region < 2) {
      // Cs[m][n] (stride 136): scalar bf16 writes, coalesced row reads.
#pragma unroll
      for (int i = 0; i < 2; ++i)
#pragma unroll
        for (int j = 0; j < 4; ++j) {
          const int nt = wn + j * 16 + col;
          const float bs = bias[nlbase + nt];
#pragma unroll
          for (int r = 0; r < 4; ++r) {
            const int mt = wm + i * 16 + quad * 4 + r;
            Cs[mt * 136 + nt] = f2bf((acc[i][j][r] + bs) * scl);
          }
        }
      __syncthreads();
      unsigned short* dst = (region == 0) ? oq : ok;
#pragma unroll
      for (int s = 0; s < 4; ++s) {
        const int u = s * 512 + tid;          // 2048 units: 128m x 2h x 8ch
        const int mt = u >> 4, hs = (u >> 3) & 1, ch = u & 7;
        const size_t g = ((size_t)(b * HH + h0 + hs) * TT + t0 + mt) * DD + ch * 8;
        *(uint4*)(dst + g) = *(const uint4*)(Cs + mt * 136 + hs * 64 + ch * 8);
      }
    } else {
      // V: Cs[n][m] (stride 136): packed b64 writes, coalesced row reads.
#pragma unroll
      for (int i = 0; i < 2; ++i)
#pragma unroll
        for (int j = 0; j < 4; ++j) {
          const int nt = wn + j * 16 + col;
          const float bs = bias[nlbase + nt];
          ushort4 pk;
          pk.x = f2bf(acc[i][j][0] + bs);
          pk.y = f2bf(acc[i][j][1] + bs);
          pk.z = f2bf(acc[i][j][2] + bs);
          pk.w = f2bf(acc[i][j][3] + bs);
          *(ushort4*)(Cs + nt * 136 + wm + i * 16 + quad * 4) = pk;
        }
      __syncthreads();
#pragma unroll
      for (int s = 0; s < 4; ++s) {
        const int u = s * 512 + tid;          // 2048 units: 128n x 16ch(m)
        const int nt = u >> 4, ch = u & 15;
        const int d = nt & 63, hs = nt >> 6;
        const size_t g = ((size_t)(b * HH + h0 + hs) * DD + d) * TT + t0 + ch * 8;
        *(uint4*)(ov + g) = *(const uint4*)(Cs + nt * 136 + ch * 8);
      }
    }
  } else {
#pragma unroll
    for (int i = 0; i < 2; ++i) {
#pragma unroll
      for (int j = 0; j < JN; ++j) {
        const int n = n0 + wn + j * 16 + col;
        const float bs = b0p[n];
#pragma unroll
        for (int r = 0; r < 4; ++r) {
          const int m = m0 + wm + i * 16 + quad * 4 + r;
          ofp[(size_t)m * EE + n] = acc[i][j][r] + bs;
        }
      }
    }
  }
  __syncthreads();   // protect S reuse across grid-stride tile loop
}

// ---------------------------------------------------------------------------
// MFMA flash attention tile body (R9 code on a shared LDS blob).
// 512 threads / 8 waves, 32x32x16 MFMA; wq = wv&3 owns 32 q-rows, wk2 =
// wv>>2 owns a 32-k half (O merged in epilogue). Max-free softmax p=2^s;
// in-register P via cvt_pk+permlane32_swap; depth-XOR swizzle (0 bank
// conflicts, R9-verified); K/V quad-buffered, 2-ahead prefetch, counted
// vmcnt(2), 1 barrier/tile.
// Blob layout (ushorts): Qs[0,8192) | Ks 4x4096 [8192,24576) | Vts 4x4096
// [24576,40960) = 80 KB.
// ---------------------------------------------------------------------------
__device__ __forceinline__ void flash_body(
    int gid, unsigned short* BLOB,
    const unsigned short* Qb, const unsigned short* Kb,
    const unsigned short* Vtb, unsigned short* ctx)
{
  unsigned short* Qs   = BLOB;
  unsigned short* Ksb  = BLOB + 8192;
  unsigned short* Vtsb = BLOB + 24576;

  const int tid  = threadIdx.x;
  const int lane = tid & 63;
  const int wv   = tid >> 6;                   // 0..7
  const int lq   = lane & 31;                  // q- or k-local index
  const int hf   = lane >> 5;                  // lane half
  const int wq   = wv & 3;                     // q-block 32*wq
  const int wk2  = wv >> 2;                    // k-half 32*wk2
  const int bh   = gid & 31;                   // XCD = gid%8 = bh%8
  const int q0   = (gid >> 5) * 128;

  const unsigned short* Qg = Qb  + (size_t)bh * TT * DD;
  const unsigned short* Kg = Kb  + (size_t)bh * TT * DD;
  const unsigned short* Vg = Vtb + (size_t)bh * DD * TT;

  const int srow = lane >> 3;                                // 8 rows/call
  const int swb  = ((lane & 7) ^ (lane >> 3)) << 3;          // base placement

  // ---- staging (waves 0-3: K, waves 4-7: V^T) ----------------------------
  const int rbK = wq * 16;
  const bool isK = (wv < 4);
  const int sw0 = swb ^ ((((rbK    ) >> 3) & 7) << 3);
  const int sw1 = swb ^ ((((rbK + 8) >> 3) & 7) << 3);
  const unsigned short* g0 =
      (isK ? Kg + (size_t)(rbK + srow) * DD : Vg + (size_t)(rbK + srow) * TT) + sw0;
  const unsigned short* g1 =
      (isK ? Kg + (size_t)(rbK + 8 + srow) * DD : Vg + (size_t)(rbK + 8 + srow) * TT) + sw1;
  unsigned short* l0 = (isK ? Ksb : Vtsb) + rbK * 64;
  unsigned short* l1 = l0 + 8 * 64;
  const int gstep = isK ? 64 * DD : 64;        // ushorts per k-tile advance

  auto stage_kv = [&](int ti, int slot) {
    const size_t go = (size_t)ti * gstep;
    async16(g0 + go, l0 + slot * 4096);
    async16(g1 + go, l1 + slot * 4096);
  };

  // ---- loop-invariant fragment byte offsets (depth-XOR swizzled) ---------
  const int l7 = lane & 7;
  const int d3 = lq >> 3;
  int koff[4], voff[2][2];
#pragma unroll
  for (int s = 0; s < 4; ++s)
    koff[s] = ((wk2 * 32 + lq) * 64 +
               (((2 * s + hf) ^ l7 ^ ((wk2 * 4 + d3) & 7)) << 3)) * 2;
#pragma unroll
  for (int m = 0; m < 2; ++m)
#pragma unroll
    for (int sg = 0; sg < 2; ++sg)
      voff[m][sg] = ((m * 32 + lq) * 64 +
                     (((wk2 * 4 + 2 * sg + hf) ^ l7 ^ ((m * 4 + d3) & 7)) << 3)) * 2;

  // stage Q (128x64) + K/V tiles 0,1
#pragma unroll
  for (int s = 0; s < 2; ++s) {
    const int rb = wv * 16 + s * 8;
    const int sq = swb ^ (((rb >> 3) & 7) << 3);
    async16(Qg + (size_t)(q0 + rb + srow) * DD + sq, &Qs[rb * 64]);
  }
  stage_kv(0, 0);
  stage_kv(1, 1);
  __syncthreads();                             // Q + KV0 + KV1 visible

  // hoist Q fragments (B-operand of S^T)
  bf16x8 aq[4];
#pragma unroll
  for (int s = 0; s < 4; ++s)
    aq[s] = *(const bf16x8*)(Qs + (wq * 32 + lq) * 64 +
                             (((2 * s + hf) ^ l7 ^ ((wq * 4 + d3) & 7)) << 3));

  const f32x16 z16 = {0.f,0.f,0.f,0.f,0.f,0.f,0.f,0.f,
                      0.f,0.f,0.f,0.f,0.f,0.f,0.f,0.f};
  f32x16 o_acc[2], sacc, nsacc;
  o_acc[0] = z16; o_acc[1] = z16;
  float lpart = 0.f;

  // prologue QK(0)
  {
    const char* Kp = (const char*)Ksb;
    bf16x8 ak = *(const bf16x8*)(Kp + koff[0]);
    sacc = __builtin_amdgcn_mfma_f32_32x32x16_bf16(ak, aq[0], z16, 0, 0, 0);
#pragma unroll
    for (int s = 1; s < 4; ++s) {
      ak = *(const bf16x8*)(Kp + koff[s]);
      sacc = __builtin_amdgcn_mfma_f32_32x32x16_bf16(ak, aq[s], sacc, 0, 0, 0);
    }
  }

#define BODY(T, S0, S1, S2, DOSTAGE, DOQK, VMC, SIN, SOUT) do {               \
    if (DOSTAGE) stage_kv((T) + 2, S2);                                       \
    asm volatile("s_waitcnt vmcnt(" #VMC ")" ::: "memory");                   \
    __builtin_amdgcn_sched_barrier(0);                                        \
    __builtin_amdgcn_s_barrier();                                             \
    __builtin_amdgcn_sched_barrier(0);                                        \
    bf16x8 pa0, pa1;                                                          \
    {  /* softmax + in-register P A-frag (k-local 0..15 of wave's half) */    \
      float e0 = __builtin_amdgcn_exp2f(SIN[0]);                              \
      float e1 = __builtin_amdgcn_exp2f(SIN[1]);                              \
      float e2 = __builtin_amdgcn_exp2f(SIN[2]);                              \
      float e3 = __builtin_amdgcn_exp2f(SIN[3]);                              \
      float e4 = __builtin_amdgcn_exp2f(SIN[4]);                              \
      float e5 = __builtin_amdgcn_exp2f(SIN[5]);                              \
      float e6 = __builtin_amdgcn_exp2f(SIN[6]);                              \
      float e7 = __builtin_amdgcn_exp2f(SIN[7]);                              \
      lpart += ((e0 + e1) + (e2 + e3)) + ((e4 + e5) + (e6 + e7));             \
      unsigned int a0 = cvtpk(e0, e1), b0 = cvtpk(e4, e5);                    \
      unsigned int a1 = cvtpk(e2, e3), b1 = cvtpk(e6, e7);                    \
      plswap(a0, b0); plswap(a1, b1);                                         \
      u32x4 w = {a0, a1, b0, b1};                                             \
      pa0 = __builtin_bit_cast(bf16x8, w);                                    \
    }                                                                         \
    {  /* k-local 16..31 */                                                   \
      float e0 = __builtin_amdgcn_exp2f(SIN[8]);                              \
      float e1 = __builtin_amdgcn_exp2f(SIN[9]);                              \
      float e2 = __builtin_amdgcn_exp2f(SIN[10]);                             \
      float e3 = __builtin_amdgcn_exp2f(SIN[11]);                             \
      float e4 = __builtin_amdgcn_exp2f(SIN[12]);                             \
      float e5 = __builtin_amdgcn_exp2f(SIN[13]);                             \
      float e6 = __builtin_amdgcn_exp2f(SIN[14]);                             \
      float e7 = __builtin_amdgcn_exp2f(SIN[15]);                             \
      lpart += ((e0 + e1) + (e2 + e3)) + ((e4 + e5) + (e6 + e7));             \
      unsigned int a0 = cvtpk(e0, e1), b0 = cvtpk(e4, e5);                    \
      unsigned int a1 = cvtpk(e2, e3), b1 = cvtpk(e6, e7);                    \
      plswap(a0, b0); plswap(a1, b1);                                         \
      u32x4 w = {a0, a1, b0, b1};                                             \
      pa1 = __builtin_bit_cast(bf16x8, w);                                    \
    }                                                                         \
    __builtin_amdgcn_s_setprio(1);                                            \
    if (DOQK) {  /* QK(t+1) direct into SOUT */                               \
      const char* Kp = (const char*)(Ksb + (S1) * 4096);                      \
      bf16x8 ak = *(const bf16x8*)(Kp + koff[0]);                             \
      SOUT = __builtin_amdgcn_mfma_f32_32x32x16_bf16(ak, aq[0], z16, 0, 0, 0);\
      _Pragma("unroll")                                                       \
      for (int s = 1; s < 4; ++s) {                                           \
        ak = *(const bf16x8*)(Kp + koff[s]);                                  \
        SOUT = __builtin_amdgcn_mfma_f32_32x32x16_bf16(ak, aq[s], SOUT, 0, 0, 0); \
      }                                                                       \
    }                                                                         \
    {  /* PV(t) */                                                            \
      const char* Vp = (const char*)(Vtsb + (S0) * 4096);                     \
      _Pragma("unroll")                                                       \
      for (int m = 0; m < 2; ++m) {                                           \
        bf16x8 v0 = *(const bf16x8*)(Vp + voff[m][0]);                        \
        bf16x8 v1 = *(const bf16x8*)(Vp + voff[m][1]);                        \
        o_acc[m] = __builtin_amdgcn_mfma_f32_32x32x16_bf16(pa0, v0, o_acc[m], 0, 0, 0); \
        o_acc[m] = __builtin_amdgcn_mfma_f32_32x32x16_bf16(pa1, v1, o_acc[m], 0, 0, 0); \
      }                                                                       \
    }                                                                         \
    __builtin_amdgcn_s_setprio(0);                                            \
  } while (0)

  for (int t = 0; t < 28; t += 4) {
    BODY(t + 0, 0, 1, 2, 1, 1, 2, sacc, nsacc);
    BODY(t + 1, 1, 2, 3, 1, 1, 2, nsacc, sacc);
    BODY(t + 2, 2, 3, 0, 1, 1, 2, sacc, nsacc);
    BODY(t + 3, 3, 0, 1, 1, 1, 2, nsacc, sacc);
  }
  BODY(28, 0, 1, 2, 1, 1, 2, sacc, nsacc);
  BODY(29, 1, 2, 3, 1, 1, 2, nsacc, sacc);
  BODY(30, 2, 3, 0, 0, 1, 0, sacc, nsacc);
  BODY(31, 3, 0, 1, 0, 0, 0, nsacc, sacc);
#undef BODY

  // ---- Epilogue: l wave-pair reduce, O wave-pair merge, normalize, store --
  float* Qf = (float*)Qs;                      // l exchange (Q area dead)
  float* Of = (float*)Ksb;                     // partial-O (K area dead)
  unsigned short* Cs = Vtsb;                   // 16 KB out bounce
  const int bq = bh >> 4, head = bh & 15;

  float lw = lpart + __shfl_xor(lpart, 32);    // wave's 32-k half, q = lq
  if (lane < 32) Qf[wv * 32 + lane] = lw;
  __syncthreads();

  if (wv >= 4) {                               // dump partials
#pragma unroll
    for (int m = 0; m < 2; ++m)
#pragma unroll
      for (int r = 0; r < 16; ++r) {
        const int ql = (r & 3) + 8 * (r >> 2) + 4 * hf;
        Of[wq * 2048 + ql * 64 + m * 32 + lq] = o_acc[m][r];
      }
  }
  __syncthreads();

  if (wv < 4) {                                // merge + normalize -> Cs
    float linv[16];
#pragma unroll
    for (int r = 0; r < 16; ++r) {
      const int ql = (r & 3) + 8 * (r >> 2) + 4 * hf;
      linv[r] = 1.0f / (Qf[wv * 32 + ql] + Qf[(wv + 4) * 32 + ql]);
    }
#pragma unroll
    for (int m = 0; m < 2; ++m)
#pragma unroll
      for (int r = 0; r < 16; ++r) {
        const int ql = (r & 3) + 8 * (r >> 2) + 4 * hf;
        const float val =
            (o_acc[m][r] + Of[wq * 2048 + ql * 64 + m * 32 + lq]) * linv[r];
        const int row = wq * 32 + ql, d = m * 32 + lq;
        Cs[row * 64 + (((d >> 3) ^ (row & 7)) << 3) + (d & 7)] = f2bf(val);
      }
  }
  __syncthreads();

#pragma unroll
  for (int s = 0; s < 2; ++s) {
    const int u = s * 512 + tid;        // 1024 units: 128 rows x 8 chunks
    const int mr = u >> 3, ch = u & 7;
    const size_t g = ((size_t)(bq * TT + q0 + mr)) * EE + head * DD + ch * 8;
    const int chs = (ch ^ (mr & 7)) << 3;
    *(uint4*)(ctx + g) = *(const uint4*)(Cs + mr * 64 + chs);
  }
  __syncthreads();   // protect blob reuse across grid-stride loop
}

// ---------------------------------------------------------------------------
// K1: [fp32->bf16 convert (x, Wq||Wk||Wv, Wo)] -> grid.sync -> [QKV GEMM].
// 768 blocks x 512 thr, LDS 48 KB -> exactly 3 blocks/CU co-resident.
// Grid-stride loops everywhere so any granted grid size is correct.
// ---------------------------------------------------------------------------
__global__ __launch_bounds__(512, 6) void qkv_fused(
    const float* __restrict__ x,  const float* __restrict__ wq,
    const float* __restrict__ wk, const float* __restrict__ wv,
    const float* __restrict__ wo,
    const float* __restrict__ bqp, const float* __restrict__ bkp,
    const float* __restrict__ bvp,
    unsigned short* __restrict__ xh, unsigned short* __restrict__ wcat,
    unsigned short* __restrict__ woh,
    unsigned short* __restrict__ oq, unsigned short* __restrict__ ok,
    unsigned short* __restrict__ ov, float qscale)
{
  __shared__ unsigned short S[24576];   // 48 KB: A 3x4096 | B 3x4096 @ 12288

  // phase 1: convert 2M float4 chunks (x 1M, Wq/Wk/Wv 256K each, Wo 256K)
  const int gsz = gridDim.x * 512;
  for (int c = blockIdx.x * 512 + threadIdx.x; c < 2097152; c += gsz) {
    const float* src; unsigned short* dst; int off;
    if (c < 1048576) { src = x; dst = xh; off = c; }
    else {
      int r = c - 1048576;
      int w = r >> 18;
      off = r & 262143;
      if      (w == 0) { src = wq; dst = wcat; }
      else if (w == 1) { src = wk; dst = wcat + (1 << 20); }
      else if (w == 2) { src = wv; dst = wcat + (2 << 20); }
      else             { src = wo; dst = woh; }
    }
    float4 v = ((const float4*)src)[off];
    ushort4 h;
    h.x = f2bf(v.x); h.y = f2bf(v.y); h.z = f2bf(v.z); h.w = f2bf(v.w);
    ((ushort4*)dst)[off] = h;
  }
  __threadfence();
  cg::this_grid().sync();

  // phase 2: QKV GEMM, 768 tiles (32 m x 24 n)
  for (int tile = blockIdx.x; tile < 768; tile += gridDim.x) {
    const int m0 = (tile & 31) * 128;
    const int n0 = (tile >> 5) * 128;
    gemm_body<0>(S, m0, n0, xh, wcat, bqp, bkp, bvp, oq, ok, ov, nullptr, qscale);
  }
}

// ---------------------------------------------------------------------------
// K2: [flash attention] -> grid.sync -> [out-proj GEMM].
// 512 blocks x 512 thr, LDS 80 KB -> exactly 2 blocks/CU co-resident.
// ---------------------------------------------------------------------------
__global__ __launch_bounds__(512, 4) void attn_out_fused(
    const unsigned short* __restrict__ Qb, const unsigned short* __restrict__ Kb,
    const unsigned short* __restrict__ Vtb, unsigned short* __restrict__ ctx,
    const unsigned short* __restrict__ woh, const float* __restrict__ bop,
    float* __restrict__ outp)
{
  __shared__ unsigned short BLOB[40960];   // 80 KB

  for (int g = blockIdx.x; g < 512; g += gridDim.x)
    flash_body(g, BLOB, Qb, Kb, Vtb, ctx);

  __threadfence();
  cg::this_grid().sync();

  // out-proj: 512 tiles (32 m x 16 n), fp32 out
  for (int g = blockIdx.x; g < 512; g += gridDim.x) {
    const int m0 = (g & 31) * 128;
    const int n0 = (g >> 5) * 64;
    gemm_body<2>(BLOB, m0, n0, ctx, woh, bop, nullptr, nullptr,
                 nullptr, nullptr, nullptr, outp, 1.0f);
  }
}

// ---------------------------------------------------------------------------
extern "C" void kernel_launch(void* const* d_in, const int* in_sizes, int n_in,
                              void* d_out, int out_size, void* d_ws, size_t ws_size,
                              hipStream_t stream) {
  const float* x  = (const float*)d_in[0];
  const float* Wq = (const float*)d_in[1];
  const float* bq = (const float*)d_in[2];
  const float* Wk = (const float*)d_in[3];
  const float* bk = (const float*)d_in[4];
  const float* Wv = (const float*)d_in[5];
  const float* bv = (const float*)d_in[6];
  const float* Wo = (const float*)d_in[7];
  const float* bo = (const float*)d_in[8];
  float* outp = (float*)d_out;

  unsigned short* p = (unsigned short*)d_ws;
  const size_t XN = (size_t)MM * EE;   // 4M
  const size_t WN = (size_t)EE * EE;   // 1M
  unsigned short* x_h    = p;           p += XN;
  unsigned short* Wcat_h = p;           p += 3 * WN;  // Wq||Wk||Wv rows
  unsigned short* Wo_h   = p;           p += WN;
  unsigned short* Qb     = p;           p += XN;
  unsigned short* Kb     = p;           p += XN;
  unsigned short* Vtb    = p;           p += XN;
  unsigned short* ctx_h  = x_h;         // x_h dead after QKV GEMM

  float qscale = 0.125f * 1.44269504088896f;   // fold log2e for exp2

  // Cooperative co-residency: query and cap (grid-stride keeps correctness
  // at any granted size; expected g1 = 768 = 3/CU, g2 = 512 = 2/CU).
  int nb1 = 0, nb2 = 0;
  (void)hipOccupancyMaxActiveBlocksPerMultiprocessor(
      &nb1, reinterpret_cast<const void*>(&qkv_fused), 512, 0);
  (void)hipOccupancyMaxActiveBlocksPerMultiprocessor(
      &nb2, reinterpret_cast<const void*>(&attn_out_fused), 512, 0);
  int g1 = nb1 * 256; if (g1 > 768 || g1 <= 0) g1 = (g1 <= 0) ? 256 : 768;
  int g2 = nb2 * 256; if (g2 > 512 || g2 <= 0) g2 = (g2 <= 0) ? 256 : 512;

  {
    void* args[] = {(void*)&x, (void*)&Wq, (void*)&Wk, (void*)&Wv, (void*)&Wo,
                    (void*)&bq, (void*)&bk, (void*)&bv,
                    (void*)&x_h, (void*)&Wcat_h, (void*)&Wo_h,
                    (void*)&Qb, (void*)&Kb, (void*)&Vtb, (void*)&qscale};
    hipLaunchCooperativeKernel(reinterpret_cast<const void*>(&qkv_fused),
                               dim3(g1), dim3(512), args, 0, stream);
  }
  {
    void* args[] = {(void*)&Qb, (void*)&Kb, (void*)&Vtb, (void*)&ctx_h,
                    (void*)&Wo_h, (void*)&bo, (void*)&outp};
    hipLaunchCooperativeKernel(reinterpret_cast<const void*>(&attn_out_fused),
                               dim3(g2), dim3(512), args, 0, stream);
  }
}

// Round 11
// 215.984 us; speedup vs baseline: 2.2417x; 2.2417x over previous
//
#include <hip/hip_runtime.h>
#include <math.h>

#define BB 2
#define TT 2048
#define EE 1024
#define HH 16
#define DD 64
#define MM (BB*TT)   // 4096
#define KK EE        // 1024

typedef short bf16x8 __attribute__((ext_vector_type(8)));
typedef float f32x4  __attribute__((ext_vector_type(4)));
typedef float f32x16 __attribute__((ext_vector_type(16)));
typedef unsigned int u32x4 __attribute__((ext_vector_type(4)));

// round-to-nearest-even fp32 -> bf16 (as ushort)
__device__ __forceinline__ unsigned short f2bf(float f) {
  unsigned int u = __float_as_uint(f);
  u = (u + 0x7FFFu + ((u >> 16) & 1u)) >> 16;
  return (unsigned short)u;
}

// packed RNE fp32x2 -> bf16x2 (low = lo)
__device__ __forceinline__ unsigned int cvtpk(float lo, float hi) {
  unsigned int r;
  asm("v_cvt_pk_bf16_f32 %0, %1, %2" : "=v"(r) : "v"(lo), "v"(hi));
  return r;
}

// (a,b) -> a = {a_lo, b_lo}, b = {a_hi, b_hi}  (32-lane half swap)
__device__ __forceinline__ void plswap(unsigned int &a, unsigned int &b) {
  asm("v_permlane32_swap_b32 %0, %1" : "+v"(a), "+v"(b));
}

// async global->LDS DMA, 16B per lane, LDS dest = wave-uniform base + lane*16
__device__ __forceinline__ void async16(const void* g, void* l) {
  __builtin_amdgcn_global_load_lds(
      (const __attribute__((address_space(1))) unsigned int*)g,
      (__attribute__((address_space(3))) unsigned int*)l, 16, 0, 0);
}

// ---------------------------------------------------------------------------
// Kernel 1: fused QKV GEMM with ON-THE-FLY fp32->bf16 conversion (replaces
// the separate to_bf16 dispatch + one kernel boundary; R10's cooperative
// fusion regressed 5x from spill + grid.sync cost — this needs NO cross-
// block sync since each block converts exactly what it stages).
// 512 thr / 8 waves, tile 128x128, wave = 32m x 64n (R9 index math).
// Staging (T14 issue-early/write-late): wave owns 2 chunks x 16 rows; per
// region: cvt(regs tile t) -> ds_write slot t%2 -> issue fp32 loads(t+1)
// -> lgkmcnt(0) -> s_barrier -> MFMA(t). Load latency hides under
// barrier+compute; LDS write lands in the same region as its consume so 2
// slots suffice (A 2x4096 @0, B 2x4096 @8192; Cs alias needs 17408).
// Depth-XOR placement slot = c ^ (row&3) ^ ((row>>2)&3) preserved
// (R9-verified 0 bank conflicts). Tail: grid-stride Wo fp32->bf16 convert
// (read by kernel 3 across the kernel boundary).
// ---------------------------------------------------------------------------
__global__ __launch_bounds__(512, 6) void qkv_gemm(
    const float* __restrict__ xf,
    const float* __restrict__ wqf, const float* __restrict__ wkf,
    const float* __restrict__ wvf, const float* __restrict__ wof,
    const float* __restrict__ b0p, const float* __restrict__ b1p,
    const float* __restrict__ b2p,
    unsigned short* __restrict__ oq, unsigned short* __restrict__ ok,
    unsigned short* __restrict__ ov, unsigned short* __restrict__ woh,
    float qscale)
{
  __shared__ unsigned short S[17408];

  const int tid  = threadIdx.x;
  const int lane = tid & 63;
  const int wv   = tid >> 6;                   // 0..7
  const int col  = lane & 15;
  const int quad = lane >> 4;
  const int wm = (wv & 3) * 32;
  const int wn = (wv >> 2) * 64;
  const int m0 = blockIdx.x * 128;
  const int n0 = blockIdx.y * 128;
  const int region = n0 >> 10;                 // 0=Q, 1=K, 2=V
  const int nlocal = n0 & 1023;

  const float* wsrc = (region == 0) ? wqf : (region == 1) ? wkf : wvf;

  const int srow = lane >> 2;                                // 16 rows/chunk
  const int sw16 = (((lane & 3) ^ ((lane >> 2) & 3) ^ (lane >> 4)) << 3);
  const int fswA = ((quad ^ (col & 3) ^ (col >> 2)) << 3);

  // wave wv stages chunks t = 2wv, 2wv+1: wv<4 -> A rows (x), else B rows (W)
  const bool isA = (wv < 4);
  const int rb0 = (isA ? (wv * 2) : (wv * 2 - 8)) * 16;
  const float* gsrc = isA ? xf : wsrc;
  const float* gp0 = gsrc + (size_t)((isA ? m0 : nlocal) + rb0 + srow) * KK + sw16;
  const float* gp1 = gp0 + (size_t)16 * KK;
  unsigned short* lp0 = S + (isA ? 0 : 8192) + rb0 * 32 + lane * 8;
  unsigned short* lp1 = lp0 + 16 * 32;

  // prologue: issue tile 0 loads (8 floats per chunk per lane)
  float4 la0 = *(const float4*)(gp0);
  float4 lb0 = *(const float4*)(gp0 + 4);
  float4 la1 = *(const float4*)(gp1);
  float4 lb1 = *(const float4*)(gp1 + 4);

  f32x4 acc[2][4];
  const f32x4 z = {0.f, 0.f, 0.f, 0.f};
#pragma unroll
  for (int i = 0; i < 2; ++i)
#pragma unroll
    for (int j = 0; j < 4; ++j) acc[i][j] = z;

#define QBODY(T, SL, DOISSUE) do {                                            \
    {  /* convert tile T from regs, write to slot SL */                       \
      u32x4 w0, w1;                                                           \
      w0[0] = cvtpk(la0.x, la0.y); w0[1] = cvtpk(la0.z, la0.w);               \
      w0[2] = cvtpk(lb0.x, lb0.y); w0[3] = cvtpk(lb0.z, lb0.w);               \
      w1[0] = cvtpk(la1.x, la1.y); w1[1] = cvtpk(la1.z, la1.w);               \
      w1[2] = cvtpk(lb1.x, lb1.y); w1[3] = cvtpk(lb1.z, lb1.w);               \
      *(u32x4*)(lp0 + (SL) * 4096) = w0;                                      \
      *(u32x4*)(lp1 + (SL) * 4096) = w1;                                      \
    }                                                                         \
    if (DOISSUE) {  /* issue tile T+1 fp32 loads (latency hidden by MFMA) */  \
      const int kt = ((T) + 1) * 32;                                          \
      la0 = *(const float4*)(gp0 + kt);                                       \
      lb0 = *(const float4*)(gp0 + kt + 4);                                   \
      la1 = *(const float4*)(gp1 + kt);                                       \
      lb1 = *(const float4*)(gp1 + kt + 4);                                   \
    }                                                                         \
    asm volatile("s_waitcnt lgkmcnt(0)" ::: "memory");                        \
    __builtin_amdgcn_sched_barrier(0);                                        \
    __builtin_amdgcn_s_barrier();                                             \
    __builtin_amdgcn_sched_barrier(0);                                        \
    const unsigned short* Asb = S + (SL) * 4096;                              \
    const unsigned short* Bsb = S + 8192 + (SL) * 4096;                       \
    bf16x8 bfr[4];                                                            \
    _Pragma("unroll")                                                         \
    for (int j = 0; j < 4; ++j)                                               \
      bfr[j] = *(const bf16x8*)(Bsb + (wn + j * 16 + col) * 32 + fswA);       \
    _Pragma("unroll")                                                         \
    for (int i = 0; i < 2; ++i) {                                             \
      bf16x8 af = *(const bf16x8*)(Asb + (wm + i * 16 + col) * 32 + fswA);    \
      _Pragma("unroll")                                                       \
      for (int j = 0; j < 4; ++j)                                             \
        acc[i][j] = __builtin_amdgcn_mfma_f32_16x16x32_bf16(af, bfr[j], acc[i][j], 0, 0, 0); \
    }                                                                         \
    __syncthreads();  /* slot SL free for rewrite in region T+2 */            \
  } while (0)

  for (int t = 0; t < 30; t += 2) {
    QBODY(t + 0, 0, 1);
    QBODY(t + 1, 1, 1);
  }
  QBODY(30, 0, 1);
  QBODY(31, 1, 0);
#undef QBODY

  // Epilogue (R9 MODE0). C/D: row = quad*4+r, col = lane&15 per 16x16 tile.
  unsigned short* Cs = S;
  {
    const float* bias = (region == 0) ? b0p : (region == 1) ? b1p : b2p;
    const float scl = (region == 0) ? qscale : 1.0f;
    const int h0 = nlocal >> 6;
    const int b = m0 >> 11, t0 = m0 & (TT - 1);
    if (region < 2) {
      // Cs[m][n] (stride 136): scalar bf16 writes, coalesced row reads.
#pragma unroll
      for (int i = 0; i < 2; ++i)
#pragma unroll
        for (int j = 0; j < 4; ++j) {
          const int nt = wn + j * 16 + col;
          const float bs = bias[nlocal + nt];
#pragma unroll
          for (int r = 0; r < 4; ++r) {
            const int mt = wm + i * 16 + quad * 4 + r;
            Cs[mt * 136 + nt] = f2bf((acc[i][j][r] + bs) * scl);
          }
        }
      __syncthreads();
      unsigned short* dst = (region == 0) ? oq : ok;
#pragma unroll
      for (int s = 0; s < 4; ++s) {
        const int u = s * 512 + tid;          // 2048 units: 128m x 2h x 8ch
        const int mt = u >> 4, hs = (u >> 3) & 1, ch = u & 7;
        const size_t g = ((size_t)(b * HH + h0 + hs) * TT + t0 + mt) * DD + ch * 8;
        *(uint4*)(dst + g) = *(const uint4*)(Cs + mt * 136 + hs * 64 + ch * 8);
      }
    } else {
      // V: Cs[n][m] (stride 136): packed b64 writes, coalesced row reads.
#pragma unroll
      for (int i = 0; i < 2; ++i)
#pragma unroll
        for (int j = 0; j < 4; ++j) {
          const int nt = wn + j * 16 + col;
          const float bs = bias[nlocal + nt];
          ushort4 pk;
          pk.x = f2bf(acc[i][j][0] + bs);
          pk.y = f2bf(acc[i][j][1] + bs);
          pk.z = f2bf(acc[i][j][2] + bs);
          pk.w = f2bf(acc[i][j][3] + bs);
          *(ushort4*)(Cs + nt * 136 + wm + i * 16 + quad * 4) = pk;
        }
      __syncthreads();
#pragma unroll
      for (int s = 0; s < 4; ++s) {
        const int u = s * 512 + tid;          // 2048 units: 128n x 16ch(m)
        const int nt = u >> 4, ch = u & 15;
        const int d = nt & 63, hs = nt >> 6;
        const size_t g = ((size_t)(b * HH + h0 + hs) * DD + d) * TT + t0 + ch * 8;
        *(uint4*)(ov + g) = *(const uint4*)(Cs + nt * 136 + ch * 8);
      }
    }
  }

  // Tail: convert Wo fp32 -> bf16 (262144 float4 chunks over 768 blocks).
  // Read by the MODE2 kernel; kernel-boundary ordering guarantees visibility.
  const int bid = blockIdx.y * gridDim.x + blockIdx.x;
  for (int c = bid * 512 + tid; c < 262144; c += 768 * 512) {
    float4 v = ((const float4*)wof)[c];
    ushort4 h;
    h.x = f2bf(v.x); h.y = f2bf(v.y); h.z = f2bf(v.z); h.w = f2bf(v.w);
    ((ushort4*)woh)[c] = h;
  }
}

// ---------------------------------------------------------------------------
// Kernel 3: bf16 MFMA GEMM (R9 verbatim; only MODE 2 instantiated).
// Triple-buffered single-barrier pipeline, 1-ahead async16 staging, counted
// vmcnt(2); depth-XOR placement (0 bank conflicts, R9-verified).
// MODE 2: fp32 out [m,EE], tile 128x64.
// ---------------------------------------------------------------------------
template<int MODE>
__global__ __launch_bounds__(512, 6) void gemm_bf16(
    const unsigned short* __restrict__ A, const unsigned short* __restrict__ B,
    const float* __restrict__ b0p, const float* __restrict__ b1p,
    const float* __restrict__ b2p,
    unsigned short* __restrict__ oq, unsigned short* __restrict__ ok,
    unsigned short* __restrict__ ov, float* __restrict__ ofp, float qscale)
{
  constexpr int NT = (MODE == 0) ? 128 : 64;   // n-tile
  constexpr int JN = NT / 32;                  // j-frags per wave (4 / 2)
  constexpr int BROWS = NT * 32;               // B-buffer ushorts per slot
  constexpr int TOT = (MODE == 0) ? 16 : 12;   // staging chunks per K-step
  __shared__ unsigned short S[12288 + 3 * BROWS];

  const int tid  = threadIdx.x;
  const int lane = tid & 63;
  const int wv   = tid >> 6;                   // 0..7
  const int col  = lane & 15;
  const int quad = lane >> 4;
  const int wm = (wv & 3) * 32;
  const int wn = (wv >> 2) * (NT / 2);
  const int m0 = blockIdx.x * 128;
  const int n0 = blockIdx.y * NT;

  const int srow = lane >> 2;                                // 16 rows/call
  const int sw16 = (((lane & 3) ^ ((lane >> 2) & 3) ^ (lane >> 4)) << 3);
  const int fswA = ((quad ^ (col & 3) ^ (col >> 2)) << 3);

  auto stage = [&](int kt, int slot) {
#pragma unroll
    for (int s = 0; s < 2; ++s) {
      const int t = wv * 2 + s;
      if (t < TOT) {
        const unsigned short* src; int rb, g0, loff;
        if (t < 8) { src = A; rb = t * 16;       g0 = m0; loff = slot * 4096; }
        else       { src = B; rb = (t - 8) * 16; g0 = n0; loff = 12288 + slot * BROWS; }
        async16(src + (size_t)(g0 + rb + srow) * KK + kt + sw16,
                S + loff + rb * 32);
      }
    }
  };

  f32x4 acc[2][JN];
  const f32x4 z = {0.f, 0.f, 0.f, 0.f};
#pragma unroll
  for (int i = 0; i < 2; ++i)
#pragma unroll
    for (int j = 0; j < JN; ++j) acc[i][j] = z;

  stage(0, 0);

#define GBODY(T, SL, S2, DOSTAGE, VMC) do {                                   \
    if (DOSTAGE) stage(((T) + 1) * 32, S2);                                   \
    asm volatile("s_waitcnt vmcnt(" #VMC ")" ::: "memory");                   \
    __builtin_amdgcn_sched_barrier(0);                                        \
    __builtin_amdgcn_s_barrier();                                             \
    __builtin_amdgcn_sched_barrier(0);                                        \
    const unsigned short* Asb = S + (SL) * 4096;                              \
    const unsigned short* Bsb = S + 12288 + (SL) * BROWS;                     \
    bf16x8 bfr[JN];                                                           \
    _Pragma("unroll")                                                         \
    for (int j = 0; j < JN; ++j)                                              \
      bfr[j] = *(const bf16x8*)(Bsb + (wn + j * 16 + col) * 32 + fswA);       \
    _Pragma("unroll")                                                         \
    for (int i = 0; i < 2; ++i) {                                             \
      bf16x8 af = *(const bf16x8*)(Asb + (wm + i * 16 + col) * 32 + fswA);    \
      _Pragma("unroll")                                                       \
      for (int j = 0; j < JN; ++j)                                            \
        acc[i][j] = __builtin_amdgcn_mfma_f32_16x16x32_bf16(af, bfr[j], acc[i][j], 0, 0, 0); \
    }                                                                         \
  } while (0)

  for (int t = 0; t < 30; t += 3) {
    GBODY(t + 0, 0, 1, 1, 2);
    GBODY(t + 1, 1, 2, 1, 2);
    GBODY(t + 2, 2, 0, 1, 2);
  }
  GBODY(30, 0, 1, 1, 2);
  GBODY(31, 1, 0, 0, 0);
#undef GBODY

  // Epilogue. C/D: row = quad*4+r, col = lane&15 per 16x16 tile.
  unsigned short* Cs = S;
  if (MODE == 0) {
    __syncthreads();
    const int region = n0 >> 10;
    const float* bias = (region == 0) ? b0p : (region == 1) ? b1p : b2p;
    const float scl = (region == 0) ? qscale : 1.0f;
    const int nlbase = n0 & 1023;
    const int h0 = nlbase >> 6;
    const int b = m0 >> 11, t0 = m0 & (TT - 1);
    if (region < 2) {
#pragma unroll
      for (int i = 0; i < 2; ++i)
#pragma unroll
        for (int j = 0; j < 4; ++j) {
          const int nt = wn + j * 16 + col;
          const float bs = bias[nlbase + nt];
#pragma unroll
          for (int r = 0; r < 4; ++r) {
            const int mt = wm + i * 16 + quad * 4 + r;
            Cs[mt * 136 + nt] = f2bf((acc[i][j][r] + bs) * scl);
          }
        }
      __syncthreads();
      unsigned short* dst = (region == 0) ? oq : ok;
#pragma unroll
      for (int s = 0; s < 4; ++s) {
        const int u = s * 512 + tid;
        const int mt = u >> 4, hs = (u >> 3) & 1, ch = u & 7;
        const size_t g = ((size_t)(b * HH + h0 + hs) * TT + t0 + mt) * DD + ch * 8;
        *(uint4*)(dst + g) = *(const uint4*)(Cs + mt * 136 + hs * 64 + ch * 8);
      }
    } else {
#pragma unroll
      for (int i = 0; i < 2; ++i)
#pragma unroll
        for (int j = 0; j < 4; ++j) {
          const int nt = wn + j * 16 + col;
          const float bs = bias[nlbase + nt];
          ushort4 pk;
          pk.x = f2bf(acc[i][j][0] + bs);
          pk.y = f2bf(acc[i][j][1] + bs);
          pk.z = f2bf(acc[i][j][2] + bs);
          pk.w = f2bf(acc[i][j][3] + bs);
          *(ushort4*)(Cs + nt * 136 + wm + i * 16 + quad * 4) = pk;
        }
      __syncthreads();
#pragma unroll
      for (int s = 0; s < 4; ++s) {
        const int u = s * 512 + tid;
        const int nt = u >> 4, ch = u & 15;
        const int d = nt & 63, hs = nt >> 6;
        const size_t g = ((size_t)(b * HH + h0 + hs) * DD + d) * TT + t0 + ch * 8;
        *(uint4*)(ov + g) = *(const uint4*)(Cs + nt * 136 + ch * 8);
      }
    }
  } else {
#pragma unroll
    for (int i = 0; i < 2; ++i) {
#pragma unroll
      for (int j = 0; j < JN; ++j) {
        const int n = n0 + wn + j * 16 + col;
        const float bs = b0p[n];
#pragma unroll
        for (int r = 0; r < 4; ++r) {
          const int m = m0 + wm + i * 16 + quad * 4 + r;
          ofp[(size_t)m * EE + n] = acc[i][j][r] + bs;
        }
      }
    }
  }
}

// ---------------------------------------------------------------------------
// Kernel 2: MFMA flash attention (R9 verbatim). 512 thr / 8 waves, 32x32x16
// MFMA; wq = wv&3 owns 32 q-rows, wk2 = wv>>2 owns a 32-k half (O merged in
// epilogue). Max-free softmax p=2^s; in-register P via cvt_pk +
// permlane32_swap; depth-XOR swizzle (0 bank conflicts, R9-verified); K/V
// quad-buffered, 2-ahead prefetch, counted vmcnt(2), 1 barrier/tile.
// ---------------------------------------------------------------------------
__global__ __launch_bounds__(512, 4) void flash_mfma(
    const unsigned short* __restrict__ Qb, const unsigned short* __restrict__ Kb,
    const unsigned short* __restrict__ Vtb, unsigned short* __restrict__ ctx)
{
  __shared__ unsigned short Qs[128 * 64];      // 16 KB (lred/linv at epilogue)
  __shared__ unsigned short Ks[4][64 * 64];    // 32 KB quad-buffered
  __shared__ unsigned short Vts[4][64 * 64];   // 32 KB quad-buffered

  const int tid  = threadIdx.x;
  const int lane = tid & 63;
  const int wv   = tid >> 6;                   // 0..7
  const int lq   = lane & 31;                  // q- or k-local index
  const int hf   = lane >> 5;                  // lane half
  const int wq   = wv & 3;                     // q-block 32*wq
  const int wk2  = wv >> 2;                    // k-half 32*wk2
  const int gid  = blockIdx.x;
  const int bh   = gid & 31;                   // XCD = gid%8 = bh%8
  const int q0   = (gid >> 5) * 128;

  const unsigned short* Qg = Qb  + (size_t)bh * TT * DD;
  const unsigned short* Kg = Kb  + (size_t)bh * TT * DD;
  const unsigned short* Vg = Vtb + (size_t)bh * DD * TT;

  const int srow = lane >> 3;                                // 8 rows/call
  const int swb  = ((lane & 7) ^ (lane >> 3)) << 3;          // base placement

  // ---- staging (waves 0-3: K, waves 4-7: V^T) ----------------------------
  const int rbK = wq * 16;
  const bool isK = (wv < 4);
  const int sw0 = swb ^ ((((rbK    ) >> 3) & 7) << 3);
  const int sw1 = swb ^ ((((rbK + 8) >> 3) & 7) << 3);
  const unsigned short* g0 =
      (isK ? Kg + (size_t)(rbK + srow) * DD : Vg + (size_t)(rbK + srow) * TT) + sw0;
  const unsigned short* g1 =
      (isK ? Kg + (size_t)(rbK + 8 + srow) * DD : Vg + (size_t)(rbK + 8 + srow) * TT) + sw1;
  unsigned short* l0 = (isK ? &Ks[0][0] : &Vts[0][0]) + rbK * 64;
  unsigned short* l1 = l0 + 8 * 64;
  const int gstep = isK ? 64 * DD : 64;        // ushorts per k-tile advance

  auto stage_kv = [&](int ti, int slot) {
    const size_t go = (size_t)ti * gstep;
    async16(g0 + go, l0 + slot * 4096);
    async16(g1 + go, l1 + slot * 4096);
  };

  // ---- loop-invariant fragment byte offsets (depth-XOR swizzled) ---------
  const int l7 = lane & 7;
  const int d3 = lq >> 3;
  int koff[4], voff[2][2];
#pragma unroll
  for (int s = 0; s < 4; ++s)
    koff[s] = ((wk2 * 32 + lq) * 64 +
               (((2 * s + hf) ^ l7 ^ ((wk2 * 4 + d3) & 7)) << 3)) * 2;
#pragma unroll
  for (int m = 0; m < 2; ++m)
#pragma unroll
    for (int sg = 0; sg < 2; ++sg)
      voff[m][sg] = ((m * 32 + lq) * 64 +
                     (((wk2 * 4 + 2 * sg + hf) ^ l7 ^ ((m * 4 + d3) & 7)) << 3)) * 2;

  // stage Q (128x64) + K/V tiles 0,1
#pragma unroll
  for (int s = 0; s < 2; ++s) {
    const int rb = wv * 16 + s * 8;
    const int sq = swb ^ (((rb >> 3) & 7) << 3);
    async16(Qg + (size_t)(q0 + rb + srow) * DD + sq, &Qs[rb * 64]);
  }
  stage_kv(0, 0);
  stage_kv(1, 1);
  __syncthreads();                             // Q + KV0 + KV1 visible

  // hoist Q fragments (B-operand of S^T)
  bf16x8 aq[4];
#pragma unroll
  for (int s = 0; s < 4; ++s)
    aq[s] = *(const bf16x8*)(Qs + (wq * 32 + lq) * 64 +
                             (((2 * s + hf) ^ l7 ^ ((wq * 4 + d3) & 7)) << 3));

  const f32x16 z16 = {0.f,0.f,0.f,0.f,0.f,0.f,0.f,0.f,
                      0.f,0.f,0.f,0.f,0.f,0.f,0.f,0.f};
  f32x16 o_acc[2], sacc, nsacc;
  o_acc[0] = z16; o_acc[1] = z16;
  float lpart = 0.f;

  // prologue QK(0)
  {
    const char* Kp = (const char*)&Ks[0][0];
    bf16x8 ak = *(const bf16x8*)(Kp + koff[0]);
    sacc = __builtin_amdgcn_mfma_f32_32x32x16_bf16(ak, aq[0], z16, 0, 0, 0);
#pragma unroll
    for (int s = 1; s < 4; ++s) {
      ak = *(const bf16x8*)(Kp + koff[s]);
      sacc = __builtin_amdgcn_mfma_f32_32x32x16_bf16(ak, aq[s], sacc, 0, 0, 0);
    }
  }

#define BODY(T, S0, S1, S2, DOSTAGE, DOQK, VMC, SIN, SOUT) do {               \
    if (DOSTAGE) stage_kv((T) + 2, S2);                                       \
    asm volatile("s_waitcnt vmcnt(" #VMC ")" ::: "memory");                   \
    __builtin_amdgcn_sched_barrier(0);                                        \
    __builtin_amdgcn_s_barrier();                                             \
    __builtin_amdgcn_sched_barrier(0);                                        \
    bf16x8 pa0, pa1;                                                          \
    {  /* softmax + in-register P A-frag (k-local 0..15 of wave's half) */    \
      float e0 = __builtin_amdgcn_exp2f(SIN[0]);                              \
      float e1 = __builtin_amdgcn_exp2f(SIN[1]);                              \
      float e2 = __builtin_amdgcn_exp2f(SIN[2]);                              \
      float e3 = __builtin_amdgcn_exp2f(SIN[3]);                              \
      float e4 = __builtin_amdgcn_exp2f(SIN[4]);                              \
      float e5 = __builtin_amdgcn_exp2f(SIN[5]);                              \
      float e6 = __builtin_amdgcn_exp2f(SIN[6]);                              \
      float e7 = __builtin_amdgcn_exp2f(SIN[7]);                              \
      lpart += ((e0 + e1) + (e2 + e3)) + ((e4 + e5) + (e6 + e7));             \
      unsigned int a0 = cvtpk(e0, e1), b0 = cvtpk(e4, e5);                    \
      unsigned int a1 = cvtpk(e2, e3), b1 = cvtpk(e6, e7);                    \
      plswap(a0, b0); plswap(a1, b1);                                         \
      u32x4 w = {a0, a1, b0, b1};                                             \
      pa0 = __builtin_bit_cast(bf16x8, w);                                    \
    }                                                                         \
    {  /* k-local 16..31 */                                                   \
      float e0 = __builtin_amdgcn_exp2f(SIN[8]);                              \
      float e1 = __builtin_amdgcn_exp2f(SIN[9]);                              \
      float e2 = __builtin_amdgcn_exp2f(SIN[10]);                             \
      float e3 = __builtin_amdgcn_exp2f(SIN[11]);                             \
      float e4 = __builtin_amdgcn_exp2f(SIN[12]);                             \
      float e5 = __builtin_amdgcn_exp2f(SIN[13]);                             \
      float e6 = __builtin_amdgcn_exp2f(SIN[14]);                             \
      float e7 = __builtin_amdgcn_exp2f(SIN[15]);                             \
      lpart += ((e0 + e1) + (e2 + e3)) + ((e4 + e5) + (e6 + e7));             \
      unsigned int a0 = cvtpk(e0, e1), b0 = cvtpk(e4, e5);                    \
      unsigned int a1 = cvtpk(e2, e3), b1 = cvtpk(e6, e7);                    \
      plswap(a0, b0); plswap(a1, b1);                                         \
      u32x4 w = {a0, a1, b0, b1};                                             \
      pa1 = __builtin_bit_cast(bf16x8, w);                                    \
    }                                                                         \
    __builtin_amdgcn_s_setprio(1);                                            \
    if (DOQK) {  /* QK(t+1) direct into SOUT */                               \
      const char* Kp = (const char*)&Ks[S1][0];                               \
      bf16x8 ak = *(const bf16x8*)(Kp + koff[0]);                             \
      SOUT = __builtin_amdgcn_mfma_f32_32x32x16_bf16(ak, aq[0], z16, 0, 0, 0);\
      _Pragma("unroll")                                                       \
      for (int s = 1; s < 4; ++s) {                                           \
        ak = *(const bf16x8*)(Kp + koff[s]);                                  \
        SOUT = __builtin_amdgcn_mfma_f32_32x32x16_bf16(ak, aq[s], SOUT, 0, 0, 0); \
      }                                                                       \
    }                                                                         \
    {  /* PV(t) */                                                            \
      const char* Vp = (const char*)&Vts[S0][0];                              \
      _Pragma("unroll")                                                       \
      for (int m = 0; m < 2; ++m) {                                           \
        bf16x8 v0 = *(const bf16x8*)(Vp + voff[m][0]);                        \
        bf16x8 v1 = *(const bf16x8*)(Vp + voff[m][1]);                        \
        o_acc[m] = __builtin_amdgcn_mfma_f32_32x32x16_bf16(pa0, v0, o_acc[m], 0, 0, 0); \
        o_acc[m] = __builtin_amdgcn_mfma_f32_32x32x16_bf16(pa1, v1, o_acc[m], 0, 0, 0); \
      }                                                                       \
    }                                                                         \
    __builtin_amdgcn_s_setprio(0);                                            \
  } while (0)

  for (int t = 0; t < 28; t += 4) {
    BODY(t + 0, 0, 1, 2, 1, 1, 2, sacc, nsacc);
    BODY(t + 1, 1, 2, 3, 1, 1, 2, nsacc, sacc);
    BODY(t + 2, 2, 3, 0, 1, 1, 2, sacc, nsacc);
    BODY(t + 3, 3, 0, 1, 1, 1, 2, nsacc, sacc);
  }
  BODY(28, 0, 1, 2, 1, 1, 2, sacc, nsacc);
  BODY(29, 1, 2, 3, 1, 1, 2, nsacc, sacc);
  BODY(30, 2, 3, 0, 0, 1, 0, sacc, nsacc);
  BODY(31, 3, 0, 1, 0, 0, 0, nsacc, sacc);
#undef BODY

  // ---- Epilogue: l wave-pair reduce, O wave-pair merge, normalize, store --
  float* Qf = (float*)&Qs[0];                  // l exchange (Q area dead)
  float* Of = (float*)&Ks[0][0];               // partial-O (K area dead)
  unsigned short* Cs = &Vts[0][0];             // 16 KB out bounce
  const int bq = bh >> 4, head = bh & 15;

  float lw = lpart + __shfl_xor(lpart, 32);    // wave's 32-k half, q = lq
  if (lane < 32) Qf[wv * 32 + lane] = lw;
  __syncthreads();

  if (wv >= 4) {                               // dump partials
#pragma unroll
    for (int m = 0; m < 2; ++m)
#pragma unroll
      for (int r = 0; r < 16; ++r) {
        const int ql = (r & 3) + 8 * (r >> 2) + 4 * hf;
        Of[wq * 2048 + ql * 64 + m * 32 + lq] = o_acc[m][r];
      }
  }
  __syncthreads();

  if (wv < 4) {                                // merge + normalize -> Cs
    float linv[16];
#pragma unroll
    for (int r = 0; r < 16; ++r) {
      const int ql = (r & 3) + 8 * (r >> 2) + 4 * hf;
      linv[r] = 1.0f / (Qf[wv * 32 + ql] + Qf[(wv + 4) * 32 + ql]);
    }
#pragma unroll
    for (int m = 0; m < 2; ++m)
#pragma unroll
      for (int r = 0; r < 16; ++r) {
        const int ql = (r & 3) + 8 * (r >> 2) + 4 * hf;
        const float val =
            (o_acc[m][r] + Of[wq * 2048 + ql * 64 + m * 32 + lq]) * linv[r];
        const int row = wq * 32 + ql, d = m * 32 + lq;
        Cs[row * 64 + (((d >> 3) ^ (row & 7)) << 3) + (d & 7)] = f2bf(val);
      }
  }
  __syncthreads();

#pragma unroll
  for (int s = 0; s < 2; ++s) {
    const int u = s * 512 + tid;        // 1024 units: 128 rows x 8 chunks
    const int mr = u >> 3, ch = u & 7;
    const size_t g = ((size_t)(bq * TT + q0 + mr)) * EE + head * DD + ch * 8;
    const int chs = (ch ^ (mr & 7)) << 3;
    *(uint4*)(ctx + g) = *(const uint4*)(Cs + mr * 64 + chs);
  }
}

// ---------------------------------------------------------------------------
extern "C" void kernel_launch(void* const* d_in, const int* in_sizes, int n_in,
                              void* d_out, int out_size, void* d_ws, size_t ws_size,
                              hipStream_t stream) {
  const float* x  = (const float*)d_in[0];
  const float* Wq = (const float*)d_in[1];
  const float* bq = (const float*)d_in[2];
  const float* Wk = (const float*)d_in[3];
  const float* bk = (const float*)d_in[4];
  const float* Wv = (const float*)d_in[5];
  const float* bv = (const float*)d_in[6];
  const float* Wo = (const float*)d_in[7];
  const float* bo = (const float*)d_in[8];

  unsigned short* p = (unsigned short*)d_ws;
  const size_t XN = (size_t)MM * EE;   // 4M
  const size_t WN = (size_t)EE * EE;   // 1M
  unsigned short* x_h    = p;           p += XN;   // now only used as ctx
  unsigned short* Wcat_h = p;           p += 3 * WN;  // unused (kept for layout)
  unsigned short* Wo_h   = p;           p += WN;
  unsigned short* Qb     = p;           p += XN;
  unsigned short* Kb     = p;           p += XN;
  unsigned short* Vtb    = p;           p += XN;
  unsigned short* ctx_h  = x_h;

  const float qscale = 0.125f * 1.44269504088896f;   // fold log2e for exp2

  qkv_gemm<<<dim3(MM / 128, 3 * EE / 128), 512, 0, stream>>>(
      x, Wq, Wk, Wv, Wo, bq, bk, bv, Qb, Kb, Vtb, Wo_h, qscale);

  flash_mfma<<<dim3((TT / 128) * BB * HH), 512, 0, stream>>>(Qb, Kb, Vtb, ctx_h);

  gemm_bf16<2><<<dim3(MM / 128, EE / 64), 512, 0, stream>>>(
      ctx_h, Wo_h, bo, nullptr, nullptr,
      nullptr, nullptr, nullptr, (float*)d_out, 1.0f);
}

// Round 12
// 188.738 us; speedup vs baseline: 2.5653x; 1.1444x over previous
//
#include <hip/hip_runtime.h>
#include <math.h>

#define BB 2
#define TT 2048
#define EE 1024
#define HH 16
#define DD 64
#define MM (BB*TT)   // 4096
#define KK EE        // 1024

typedef short bf16x8 __attribute__((ext_vector_type(8)));
typedef float f32x4  __attribute__((ext_vector_type(4)));
typedef float f32x16 __attribute__((ext_vector_type(16)));
typedef unsigned int u32x4 __attribute__((ext_vector_type(4)));

// round-to-nearest-even fp32 -> bf16 (as ushort)
__device__ __forceinline__ unsigned short f2bf(float f) {
  unsigned int u = __float_as_uint(f);
  u = (u + 0x7FFFu + ((u >> 16) & 1u)) >> 16;
  return (unsigned short)u;
}

// packed RNE fp32x2 -> bf16x2 (low = lo)
__device__ __forceinline__ unsigned int cvtpk(float lo, float hi) {
  unsigned int r;
  asm("v_cvt_pk_bf16_f32 %0, %1, %2" : "=v"(r) : "v"(lo), "v"(hi));
  return r;
}

// (a,b) -> a = {a_lo, b_lo}, b = {a_hi, b_hi}  (32-lane half swap)
__device__ __forceinline__ void plswap(unsigned int &a, unsigned int &b) {
  asm("v_permlane32_swap_b32 %0, %1" : "+v"(a), "+v"(b));
}

// async global->LDS DMA, 16B per lane, LDS dest = wave-uniform base + lane*16
__device__ __forceinline__ void async16(const void* g, void* l) {
  __builtin_amdgcn_global_load_lds(
      (const __attribute__((address_space(1))) unsigned int*)g,
      (__attribute__((address_space(3))) unsigned int*)l, 16, 0, 0);
}

// ---------------------------------------------------------------------------
// fp32 -> bf16 convert for x and the 4 weight matrices (R9 verbatim —
// R10 coop-fusion and R11 on-the-fly-convert both regressed: spill + extra
// fp32 traffic. This separate BW-bound dispatch (~8us at HBM peak) stays.
// ---------------------------------------------------------------------------
__global__ __launch_bounds__(256) void to_bf16(
    const float* __restrict__ x,  const float* __restrict__ wq,
    const float* __restrict__ wk, const float* __restrict__ wv,
    const float* __restrict__ wo,
    unsigned short* __restrict__ xh, unsigned short* __restrict__ wcat,
    unsigned short* __restrict__ woh)
{
  int c = blockIdx.x * 256 + threadIdx.x;
  const float* src; unsigned short* dst; int off;
  if (c < 1048576) { src = x; dst = xh; off = c; }
  else {
    int r = c - 1048576;
    int w = r >> 18;                 // 262144 chunks per W
    off = r & 262143;
    if      (w == 0) { src = wq; dst = wcat; }
    else if (w == 1) { src = wk; dst = wcat + (1 << 20); }
    else if (w == 2) { src = wv; dst = wcat + (2 << 20); }
    else             { src = wo; dst = woh; }
  }
  float4 v = ((const float4*)src)[off];
  ushort4 h;
  h.x = f2bf(v.x); h.y = f2bf(v.y); h.z = f2bf(v.z); h.w = f2bf(v.w);
  ((ushort4*)dst)[off] = h;
}

// ---------------------------------------------------------------------------
// QKV bf16 MFMA GEMM (R9 verbatim, MODE 0 only). 512 thr / 8 waves, tile
// 128x128; triple-buffered single-barrier pipeline, 1-ahead staging,
// counted vmcnt(2); depth-XOR placement (0 bank conflicts, R9-verified);
// LDS 48 KB -> 3 blocks/CU (R8: +7.5us vs 2/CU — why this kernel does NOT
// get the 2-steps/region treatment: 4 slots would be 64KB -> 2/CU).
// ---------------------------------------------------------------------------
template<int MODE>
__global__ __launch_bounds__(512, 6) void gemm_bf16(
    const unsigned short* __restrict__ A, const unsigned short* __restrict__ B,
    const float* __restrict__ b0p, const float* __restrict__ b1p,
    const float* __restrict__ b2p,
    unsigned short* __restrict__ oq, unsigned short* __restrict__ ok,
    unsigned short* __restrict__ ov, float* __restrict__ ofp, float qscale)
{
  constexpr int NT = (MODE == 0) ? 128 : 64;   // n-tile
  constexpr int JN = NT / 32;                  // j-frags per wave (4 / 2)
  constexpr int BROWS = NT * 32;               // B-buffer ushorts per slot
  constexpr int TOT = (MODE == 0) ? 16 : 12;   // staging chunks per K-step
  __shared__ unsigned short S[12288 + 3 * BROWS];

  const int tid  = threadIdx.x;
  const int lane = tid & 63;
  const int wv   = tid >> 6;                   // 0..7
  const int col  = lane & 15;
  const int quad = lane >> 4;
  const int wm = (wv & 3) * 32;
  const int wn = (wv >> 2) * (NT / 2);
  const int m0 = blockIdx.x * 128;
  const int n0 = blockIdx.y * NT;

  const int srow = lane >> 2;                                // 16 rows/call
  const int sw16 = (((lane & 3) ^ ((lane >> 2) & 3) ^ (lane >> 4)) << 3);
  const int fswA = ((quad ^ (col & 3) ^ (col >> 2)) << 3);

  auto stage = [&](int kt, int slot) {
#pragma unroll
    for (int s = 0; s < 2; ++s) {
      const int t = wv * 2 + s;
      if (t < TOT) {
        const unsigned short* src; int rb, g0, loff;
        if (t < 8) { src = A; rb = t * 16;       g0 = m0; loff = slot * 4096; }
        else       { src = B; rb = (t - 8) * 16; g0 = n0; loff = 12288 + slot * BROWS; }
        async16(src + (size_t)(g0 + rb + srow) * KK + kt + sw16,
                S + loff + rb * 32);
      }
    }
  };

  f32x4 acc[2][JN];
  const f32x4 z = {0.f, 0.f, 0.f, 0.f};
#pragma unroll
  for (int i = 0; i < 2; ++i)
#pragma unroll
    for (int j = 0; j < JN; ++j) acc[i][j] = z;

  stage(0, 0);

#define GBODY(T, SL, S2, DOSTAGE, VMC) do {                                   \
    if (DOSTAGE) stage(((T) + 1) * 32, S2);                                   \
    asm volatile("s_waitcnt vmcnt(" #VMC ")" ::: "memory");                   \
    __builtin_amdgcn_sched_barrier(0);                                        \
    __builtin_amdgcn_s_barrier();                                             \
    __builtin_amdgcn_sched_barrier(0);                                        \
    const unsigned short* Asb = S + (SL) * 4096;                              \
    const unsigned short* Bsb = S + 12288 + (SL) * BROWS;                     \
    bf16x8 bfr[JN];                                                           \
    _Pragma("unroll")                                                         \
    for (int j = 0; j < JN; ++j)                                              \
      bfr[j] = *(const bf16x8*)(Bsb + (wn + j * 16 + col) * 32 + fswA);       \
    _Pragma("unroll")                                                         \
    for (int i = 0; i < 2; ++i) {                                             \
      bf16x8 af = *(const bf16x8*)(Asb + (wm + i * 16 + col) * 32 + fswA);    \
      _Pragma("unroll")                                                       \
      for (int j = 0; j < JN; ++j)                                            \
        acc[i][j] = __builtin_amdgcn_mfma_f32_16x16x32_bf16(af, bfr[j], acc[i][j], 0, 0, 0); \
    }                                                                         \
  } while (0)

  for (int t = 0; t < 30; t += 3) {
    GBODY(t + 0, 0, 1, 1, 2);
    GBODY(t + 1, 1, 2, 1, 2);
    GBODY(t + 2, 2, 0, 1, 2);
  }
  GBODY(30, 0, 1, 1, 2);
  GBODY(31, 1, 0, 0, 0);
#undef GBODY

  // Epilogue. C/D: row = quad*4+r, col = lane&15 per 16x16 tile.
  unsigned short* Cs = S;
  if (MODE == 0) {
    __syncthreads();   // all waves done reading slots before Cs alias writes
    const int region = n0 >> 10;   // block-uniform: 0=Q, 1=K, 2=V
    const float* bias = (region == 0) ? b0p : (region == 1) ? b1p : b2p;
    const float scl = (region == 0) ? qscale : 1.0f;
    const int nlbase = n0 & 1023;
    const int h0 = nlbase >> 6;
    const int b = m0 >> 11, t0 = m0 & (TT - 1);
    if (region < 2) {
      // Cs[m][n] (stride 136): scalar bf16 writes, coalesced row reads.
#pragma unroll
      for (int i = 0; i < 2; ++i)
#pragma unroll
        for (int j = 0; j < 4; ++j) {
          const int nt = wn + j * 16 + col;
          const float bs = bias[nlbase + nt];
#pragma unroll
          for (int r = 0; r < 4; ++r) {
            const int mt = wm + i * 16 + quad * 4 + r;
            Cs[mt * 136 + nt] = f2bf((acc[i][j][r] + bs) * scl);
          }
        }
      __syncthreads();
      unsigned short* dst = (region == 0) ? oq : ok;
#pragma unroll
      for (int s = 0; s < 4; ++s) {
        const int u = s * 512 + tid;          // 2048 units: 128m x 2h x 8ch
        const int mt = u >> 4, hs = (u >> 3) & 1, ch = u & 7;
        const size_t g = ((size_t)(b * HH + h0 + hs) * TT + t0 + mt) * DD + ch * 8;
        *(uint4*)(dst + g) = *(const uint4*)(Cs + mt * 136 + hs * 64 + ch * 8);
      }
    } else {
      // V: Cs[n][m] (stride 136): packed b64 writes, coalesced row reads.
#pragma unroll
      for (int i = 0; i < 2; ++i)
#pragma unroll
        for (int j = 0; j < 4; ++j) {
          const int nt = wn + j * 16 + col;
          const float bs = bias[nlbase + nt];
          ushort4 pk;
          pk.x = f2bf(acc[i][j][0] + bs);
          pk.y = f2bf(acc[i][j][1] + bs);
          pk.z = f2bf(acc[i][j][2] + bs);
          pk.w = f2bf(acc[i][j][3] + bs);
          *(ushort4*)(Cs + nt * 136 + wm + i * 16 + quad * 4) = pk;
        }
      __syncthreads();
#pragma unroll
      for (int s = 0; s < 4; ++s) {
        const int u = s * 512 + tid;          // 2048 units: 128n x 16ch(m)
        const int nt = u >> 4, ch = u & 15;
        const int d = nt & 63, hs = nt >> 6;
        const size_t g = ((size_t)(b * HH + h0 + hs) * DD + d) * TT + t0 + ch * 8;
        *(uint4*)(ov + g) = *(const uint4*)(Cs + nt * 136 + ch * 8);
      }
    }
  } else {
#pragma unroll
    for (int i = 0; i < 2; ++i) {
#pragma unroll
      for (int j = 0; j < JN; ++j) {
        const int n = n0 + wn + j * 16 + col;
        const float bs = b0p[n];
#pragma unroll
        for (int r = 0; r < 4; ++r) {
          const int m = m0 + wm + i * 16 + quad * 4 + r;
          ofp[(size_t)m * EE + n] = acc[i][j][r] + bs;
        }
      }
    }
  }
}

// ---------------------------------------------------------------------------
// Out-proj GEMM (MODE2 shape), NEW: 2 K-steps per barrier region, 4 slots.
// R9 measured ~35us for 8.6 GF (worst MFMA-per-barrier ratio: 4 MFMA/wave
// per barrier). Region r = { vmcnt(0) ; barrier ; stage steps 2r+2,2r+3
// (post-barrier -> writes slots of steps 2r-2,2r-1, last read pre-barrier(r)
// -> race-free) ; compute steps 2r,2r+1 }. Steps 2r,2r+1 staged in region
// r-1 post-barrier: one full region (~>1000cy) of flight before the
// vmcnt(0), so the drain is cheap; 16 barriers instead of 32.
// LDS: A 4x4096 @0, B 4x2048 @16384 = 48 KB (grid-capped 2/CU regardless).
// ---------------------------------------------------------------------------
__global__ __launch_bounds__(512, 6) void gemm_out(
    const unsigned short* __restrict__ A, const unsigned short* __restrict__ B,
    const float* __restrict__ bias, float* __restrict__ ofp)
{
  __shared__ unsigned short S[24576];

  const int tid  = threadIdx.x;
  const int lane = tid & 63;
  const int wv   = tid >> 6;                   // 0..7
  const int col  = lane & 15;
  const int quad = lane >> 4;
  const int wm = (wv & 3) * 32;
  const int wn = (wv >> 2) * 32;
  const int m0 = blockIdx.x * 128;
  const int n0 = blockIdx.y * 64;

  const int srow = lane >> 2;                                // 16 rows/call
  const int sw16 = (((lane & 3) ^ ((lane >> 2) & 3) ^ (lane >> 4)) << 3);
  const int fswA = ((quad ^ (col & 3) ^ (col >> 2)) << 3);

  auto stage = [&](int kt, int slot) {
#pragma unroll
    for (int s = 0; s < 2; ++s) {
      const int t = wv * 2 + s;
      if (t < 12) {
        const unsigned short* src; int rb, g0, loff;
        if (t < 8) { src = A; rb = t * 16;       g0 = m0; loff = slot * 4096; }
        else       { src = B; rb = (t - 8) * 16; g0 = n0; loff = 16384 + slot * 2048; }
        async16(src + (size_t)(g0 + rb + srow) * KK + kt + sw16,
                S + loff + rb * 32);
      }
    }
  };

  f32x4 acc[2][2];
  const f32x4 z = {0.f, 0.f, 0.f, 0.f};
#pragma unroll
  for (int i = 0; i < 2; ++i)
#pragma unroll
    for (int j = 0; j < 2; ++j) acc[i][j] = z;

  stage(0, 0);
  stage(32, 1);

#define GCOMP(SL) do {                                                        \
    const unsigned short* Asb = S + (SL) * 4096;                              \
    const unsigned short* Bsb = S + 16384 + (SL) * 2048;                      \
    bf16x8 b0 = *(const bf16x8*)(Bsb + (wn + col) * 32 + fswA);               \
    bf16x8 b1 = *(const bf16x8*)(Bsb + (wn + 16 + col) * 32 + fswA);          \
    _Pragma("unroll")                                                         \
    for (int i = 0; i < 2; ++i) {                                             \
      bf16x8 af = *(const bf16x8*)(Asb + (wm + i * 16 + col) * 32 + fswA);    \
      acc[i][0] = __builtin_amdgcn_mfma_f32_16x16x32_bf16(af, b0, acc[i][0], 0, 0, 0); \
      acc[i][1] = __builtin_amdgcn_mfma_f32_16x16x32_bf16(af, b1, acc[i][1], 0, 0, 0); \
    }                                                                         \
} while (0)

#define REGION2(T, SLa, SLb, SSa, SSb, DOSTAGE, VMC) do {                     \
    asm volatile("s_waitcnt vmcnt(" #VMC ")" ::: "memory");                   \
    __builtin_amdgcn_sched_barrier(0);                                        \
    __builtin_amdgcn_s_barrier();                                             \
    __builtin_amdgcn_sched_barrier(0);                                        \
    if (DOSTAGE) { stage(((T) + 2) * 32, SSa); stage(((T) + 3) * 32, SSb); }  \
    GCOMP(SLa);                                                               \
    GCOMP(SLb);                                                               \
} while (0)

  for (int t = 0; t < 28; t += 4) {
    REGION2(t + 0, 0, 1, 2, 3, 1, 0);
    REGION2(t + 2, 2, 3, 0, 1, 1, 0);
  }
  REGION2(28, 0, 1, 2, 3, 1, 0);   // stages steps 30,31 -> slots 2,3
  REGION2(30, 2, 3, 0, 1, 0, 0);
#undef REGION2
#undef GCOMP

  // Epilogue: direct fp32 stores. C/D: row = quad*4+r, col = lane&15.
#pragma unroll
  for (int i = 0; i < 2; ++i) {
#pragma unroll
    for (int j = 0; j < 2; ++j) {
      const int n = n0 + wn + j * 16 + col;
      const float bs = bias[n];
#pragma unroll
      for (int r = 0; r < 4; ++r) {
        const int m = m0 + wm + i * 16 + quad * 4 + r;
        ofp[(size_t)m * EE + n] = acc[i][j][r] + bs;
      }
    }
  }
}

// ---------------------------------------------------------------------------
// MFMA flash attention, NEW: 2 k-tiles per barrier region (16 barriers, was
// 32 — R9 counters: convoy-bound, all pipes <42%, wall 3705 cyc/region vs
// 1536 max-pipe; R9's swizzle zeroed bank conflicts with no time change =
// latency/barrier regime). Same post-barrier 1-region-ahead staging scheme
// as gemm_out (race analysis identical; K/V slots keep the 4-slot layout).
// Per region: QK(a)+QK(b) (8 MFMA cluster) ; sm(a) ; PV(a) ; sm(b) ; PV(b)
// — sm(x) overlaps the other tile's MFMAs. All other machinery R9 verbatim:
// 32x32x16, max-free softmax p=2^s, in-register P via cvt_pk+permlane32,
// depth-XOR swizzle, wave grid wq/wk2, O-merge epilogue.
// ---------------------------------------------------------------------------
__global__ __launch_bounds__(512, 4) void flash_mfma(
    const unsigned short* __restrict__ Qb, const unsigned short* __restrict__ Kb,
    const unsigned short* __restrict__ Vtb, unsigned short* __restrict__ ctx)
{
  __shared__ unsigned short Qs[128 * 64];      // 16 KB (lred/linv at epilogue)
  __shared__ unsigned short Ks[4][64 * 64];    // 32 KB quad-buffered
  __shared__ unsigned short Vts[4][64 * 64];   // 32 KB quad-buffered

  const int tid  = threadIdx.x;
  const int lane = tid & 63;
  const int wv   = tid >> 6;                   // 0..7
  const int lq   = lane & 31;                  // q- or k-local index
  const int hf   = lane >> 5;                  // lane half
  const int wq   = wv & 3;                     // q-block 32*wq
  const int wk2  = wv >> 2;                    // k-half 32*wk2
  const int gid  = blockIdx.x;
  const int bh   = gid & 31;                   // XCD = gid%8 = bh%8
  const int q0   = (gid >> 5) * 128;

  const unsigned short* Qg = Qb  + (size_t)bh * TT * DD;
  const unsigned short* Kg = Kb  + (size_t)bh * TT * DD;
  const unsigned short* Vg = Vtb + (size_t)bh * DD * TT;

  const int srow = lane >> 3;                                // 8 rows/call
  const int swb  = ((lane & 7) ^ (lane >> 3)) << 3;          // base placement

  // ---- staging (waves 0-3: K, waves 4-7: V^T) ----------------------------
  const int rbK = wq * 16;
  const bool isK = (wv < 4);
  const int sw0 = swb ^ ((((rbK    ) >> 3) & 7) << 3);
  const int sw1 = swb ^ ((((rbK + 8) >> 3) & 7) << 3);
  const unsigned short* g0 =
      (isK ? Kg + (size_t)(rbK + srow) * DD : Vg + (size_t)(rbK + srow) * TT) + sw0;
  const unsigned short* g1 =
      (isK ? Kg + (size_t)(rbK + 8 + srow) * DD : Vg + (size_t)(rbK + 8 + srow) * TT) + sw1;
  unsigned short* l0 = (isK ? &Ks[0][0] : &Vts[0][0]) + rbK * 64;
  unsigned short* l1 = l0 + 8 * 64;
  const int gstep = isK ? 64 * DD : 64;        // ushorts per k-tile advance

  auto stage_kv = [&](int ti, int slot) {
    const size_t go = (size_t)ti * gstep;
    async16(g0 + go, l0 + slot * 4096);
    async16(g1 + go, l1 + slot * 4096);
  };

  // ---- loop-invariant fragment byte offsets (depth-XOR swizzled) ---------
  const int l7 = lane & 7;
  const int d3 = lq >> 3;
  int koff[4], voff[2][2];
#pragma unroll
  for (int s = 0; s < 4; ++s)
    koff[s] = ((wk2 * 32 + lq) * 64 +
               (((2 * s + hf) ^ l7 ^ ((wk2 * 4 + d3) & 7)) << 3)) * 2;
#pragma unroll
  for (int m = 0; m < 2; ++m)
#pragma unroll
    for (int sg = 0; sg < 2; ++sg)
      voff[m][sg] = ((m * 32 + lq) * 64 +
                     (((wk2 * 4 + 2 * sg + hf) ^ l7 ^ ((m * 4 + d3) & 7)) << 3)) * 2;

  // stage Q (128x64) + K/V tiles 0,1
#pragma unroll
  for (int s = 0; s < 2; ++s) {
    const int rb = wv * 16 + s * 8;
    const int sq = swb ^ (((rb >> 3) & 7) << 3);
    async16(Qg + (size_t)(q0 + rb + srow) * DD + sq, &Qs[rb * 64]);
  }
  stage_kv(0, 0);
  stage_kv(1, 1);
  __syncthreads();                             // Q + KV0 + KV1 visible

  // hoist Q fragments (B-operand of S^T)
  bf16x8 aq[4];
#pragma unroll
  for (int s = 0; s < 4; ++s)
    aq[s] = *(const bf16x8*)(Qs + (wq * 32 + lq) * 64 +
                             (((2 * s + hf) ^ l7 ^ ((wq * 4 + d3) & 7)) << 3));

  const f32x16 z16 = {0.f,0.f,0.f,0.f,0.f,0.f,0.f,0.f,
                      0.f,0.f,0.f,0.f,0.f,0.f,0.f,0.f};
  f32x16 o_acc[2];
  o_acc[0] = z16; o_acc[1] = z16;
  float lpart = 0.f;

#define SMPACK(SIN, PA0, PA1) do {                                            \
    {                                                                         \
      float e0 = __builtin_amdgcn_exp2f(SIN[0]);                              \
      float e1 = __builtin_amdgcn_exp2f(SIN[1]);                              \
      float e2 = __builtin_amdgcn_exp2f(SIN[2]);                              \
      float e3 = __builtin_amdgcn_exp2f(SIN[3]);                              \
      float e4 = __builtin_amdgcn_exp2f(SIN[4]);                              \
      float e5 = __builtin_amdgcn_exp2f(SIN[5]);                              \
      float e6 = __builtin_amdgcn_exp2f(SIN[6]);                              \
      float e7 = __builtin_amdgcn_exp2f(SIN[7]);                              \
      lpart += ((e0 + e1) + (e2 + e3)) + ((e4 + e5) + (e6 + e7));             \
      unsigned int a0 = cvtpk(e0, e1), b0 = cvtpk(e4, e5);                    \
      unsigned int a1 = cvtpk(e2, e3), b1 = cvtpk(e6, e7);                    \
      plswap(a0, b0); plswap(a1, b1);                                         \
      u32x4 w = {a0, a1, b0, b1};                                             \
      PA0 = __builtin_bit_cast(bf16x8, w);                                    \
    }                                                                         \
    {                                                                         \
      float e0 = __builtin_amdgcn_exp2f(SIN[8]);                              \
      float e1 = __builtin_amdgcn_exp2f(SIN[9]);                              \
      float e2 = __builtin_amdgcn_exp2f(SIN[10]);                             \
      float e3 = __builtin_amdgcn_exp2f(SIN[11]);                             \
      float e4 = __builtin_amdgcn_exp2f(SIN[12]);                             \
      float e5 = __builtin_amdgcn_exp2f(SIN[13]);                             \
      float e6 = __builtin_amdgcn_exp2f(SIN[14]);                             \
      float e7 = __builtin_amdgcn_exp2f(SIN[15]);                             \
      lpart += ((e0 + e1) + (e2 + e3)) + ((e4 + e5) + (e6 + e7));             \
      unsigned int a0 = cvtpk(e0, e1), b0 = cvtpk(e4, e5);                    \
      unsigned int a1 = cvtpk(e2, e3), b1 = cvtpk(e6, e7);                    \
      plswap(a0, b0); plswap(a1, b1);                                         \
      u32x4 w = {a0, a1, b0, b1};                                             \
      PA1 = __builtin_bit_cast(bf16x8, w);                                    \
    }                                                                         \
} while (0)

#define QKT(SL, SOUT) do {                                                    \
    const char* Kp = (const char*)&Ks[SL][0];                                 \
    bf16x8 ak = *(const bf16x8*)(Kp + koff[0]);                               \
    SOUT = __builtin_amdgcn_mfma_f32_32x32x16_bf16(ak, aq[0], z16, 0, 0, 0);  \
    _Pragma("unroll")                                                         \
    for (int s = 1; s < 4; ++s) {                                             \
      ak = *(const bf16x8*)(Kp + koff[s]);                                    \
      SOUT = __builtin_amdgcn_mfma_f32_32x32x16_bf16(ak, aq[s], SOUT, 0, 0, 0); \
    }                                                                         \
} while (0)

#define PVT(SL, P0, P1) do {                                                  \
    const char* Vp = (const char*)&Vts[SL][0];                                \
    _Pragma("unroll")                                                         \
    for (int m = 0; m < 2; ++m) {                                             \
      bf16x8 v0 = *(const bf16x8*)(Vp + voff[m][0]);                          \
      bf16x8 v1 = *(const bf16x8*)(Vp + voff[m][1]);                          \
      o_acc[m] = __builtin_amdgcn_mfma_f32_32x32x16_bf16(P0, v0, o_acc[m], 0, 0, 0); \
      o_acc[m] = __builtin_amdgcn_mfma_f32_32x32x16_bf16(P1, v1, o_acc[m], 0, 0, 0); \
    }                                                                         \
} while (0)

#define REGION(T, SLa, SLb, SSa, SSb, DOSTAGE) do {                           \
    asm volatile("s_waitcnt vmcnt(0)" ::: "memory");                          \
    __builtin_amdgcn_sched_barrier(0);                                        \
    __builtin_amdgcn_s_barrier();                                             \
    __builtin_amdgcn_sched_barrier(0);                                        \
    if (DOSTAGE) { stage_kv((T) + 2, SSa); stage_kv((T) + 3, SSb); }          \
    f32x16 sa, sb;                                                            \
    __builtin_amdgcn_s_setprio(1);                                            \
    QKT(SLa, sa);                                                             \
    QKT(SLb, sb);                                                             \
    __builtin_amdgcn_s_setprio(0);                                            \
    bf16x8 pa0, pa1, pb0, pb1;                                                \
    SMPACK(sa, pa0, pa1);                                                     \
    __builtin_amdgcn_s_setprio(1);                                            \
    PVT(SLa, pa0, pa1);                                                       \
    __builtin_amdgcn_s_setprio(0);                                            \
    SMPACK(sb, pb0, pb1);                                                     \
    __builtin_amdgcn_s_setprio(1);                                            \
    PVT(SLb, pb0, pb1);                                                       \
    __builtin_amdgcn_s_setprio(0);                                            \
} while (0)

  // 16 regions x 2 tiles. Region r stages tiles 2r+2,2r+3 post-barrier
  // (slots of tiles 2r-2,2r-1, last read pre-barrier(r)); consumes tiles
  // 2r,2r+1 staged in region r-1 (vmcnt(0) before barrier(r) drains them).
  for (int t = 0; t < 28; t += 4) {
    REGION(t + 0, 0, 1, 2, 3, 1);
    REGION(t + 2, 2, 3, 0, 1, 1);
  }
  REGION(28, 0, 1, 2, 3, 1);   // stages tiles 30,31 -> slots 2,3
  REGION(30, 2, 3, 0, 1, 0);
#undef REGION
#undef PVT
#undef QKT
#undef SMPACK

  // ---- Epilogue: l wave-pair reduce, O wave-pair merge, normalize, store --
  float* Qf = (float*)&Qs[0];                  // l exchange (Q area dead)
  float* Of = (float*)&Ks[0][0];               // partial-O (K area dead)
  unsigned short* Cs = &Vts[0][0];             // 16 KB out bounce
  const int bq = bh >> 4, head = bh & 15;

  float lw = lpart + __shfl_xor(lpart, 32);    // wave's 32-k half, q = lq
  if (lane < 32) Qf[wv * 32 + lane] = lw;
  __syncthreads();

  if (wv >= 4) {                               // dump partials
#pragma unroll
    for (int m = 0; m < 2; ++m)
#pragma unroll
      for (int r = 0; r < 16; ++r) {
        const int ql = (r & 3) + 8 * (r >> 2) + 4 * hf;
        Of[wq * 2048 + ql * 64 + m * 32 + lq] = o_acc[m][r];
      }
  }
  __syncthreads();

  if (wv < 4) {                                // merge + normalize -> Cs
    float linv[16];
#pragma unroll
    for (int r = 0; r < 16; ++r) {
      const int ql = (r & 3) + 8 * (r >> 2) + 4 * hf;
      linv[r] = 1.0f / (Qf[wv * 32 + ql] + Qf[(wv + 4) * 32 + ql]);
    }
#pragma unroll
    for (int m = 0; m < 2; ++m)
#pragma unroll
      for (int r = 0; r < 16; ++r) {
        const int ql = (r & 3) + 8 * (r >> 2) + 4 * hf;
        const float val =
            (o_acc[m][r] + Of[wq * 2048 + ql * 64 + m * 32 + lq]) * linv[r];
        const int row = wq * 32 + ql, d = m * 32 + lq;
        Cs[row * 64 + (((d >> 3) ^ (row & 7)) << 3) + (d & 7)] = f2bf(val);
      }
  }
  __syncthreads();

#pragma unroll
  for (int s = 0; s < 2; ++s) {
    const int u = s * 512 + tid;        // 1024 units: 128 rows x 8 chunks
    const int mr = u >> 3, ch = u & 7;
    const size_t g = ((size_t)(bq * TT + q0 + mr)) * EE + head * DD + ch * 8;
    const int chs = (ch ^ (mr & 7)) << 3;
    *(uint4*)(ctx + g) = *(const uint4*)(Cs + mr * 64 + chs);
  }
}

// ---------------------------------------------------------------------------
extern "C" void kernel_launch(void* const* d_in, const int* in_sizes, int n_in,
                              void* d_out, int out_size, void* d_ws, size_t ws_size,
                              hipStream_t stream) {
  const float* x  = (const float*)d_in[0];
  const float* Wq = (const float*)d_in[1];
  const float* bq = (const float*)d_in[2];
  const float* Wk = (const float*)d_in[3];
  const float* bk = (const float*)d_in[4];
  const float* Wv = (const float*)d_in[5];
  const float* bv = (const float*)d_in[6];
  const float* Wo = (const float*)d_in[7];
  const float* bo = (const float*)d_in[8];

  unsigned short* p = (unsigned short*)d_ws;
  const size_t XN = (size_t)MM * EE;   // 4M
  const size_t WN = (size_t)EE * EE;   // 1M
  unsigned short* x_h    = p;           p += XN;
  unsigned short* Wcat_h = p;           p += 3 * WN;  // Wq||Wk||Wv rows
  unsigned short* Wo_h   = p;           p += WN;
  unsigned short* Qb     = p;           p += XN;
  unsigned short* Kb     = p;           p += XN;
  unsigned short* Vtb    = p;           p += XN;
  unsigned short* ctx_h  = x_h;         // x_h dead after QKV GEMM

  const float qscale = 0.125f * 1.44269504088896f;   // fold log2e for exp2

  to_bf16<<<8192, 256, 0, stream>>>(x, Wq, Wk, Wv, Wo, x_h, Wcat_h, Wo_h);

  gemm_bf16<0><<<dim3(MM / 128, 3 * EE / 128), 512, 0, stream>>>(
      x_h, Wcat_h, bq, bk, bv, Qb, Kb, Vtb, nullptr, qscale);

  flash_mfma<<<dim3((TT / 128) * BB * HH), 512, 0, stream>>>(Qb, Kb, Vtb, ctx_h);

  gemm_out<<<dim3(MM / 128, EE / 64), 512, 0, stream>>>(
      ctx_h, Wo_h, bo, (float*)d_out);
}